// Round 1
// baseline (2063.139 us; speedup 1.0000x reference)
//
#include <hip/hip_runtime.h>
#include <hip/hip_bf16.h>

// Problem constants
#define BB 1024   // batch
#define HH 64     // hidden
#define LL 64     // leaves per batch

// ---------------------------------------------------------------------------
// Leaf gather: nodes[row][h] = embed[ids[row]][h], rows = B*L = 65536
// one float4 per thread; 65536 rows * 16 float4 = 1,048,576 threads
// ---------------------------------------------------------------------------
__global__ __launch_bounds__(256) void gather_leaves(
    const int* __restrict__ ids, const float* __restrict__ embed,
    float* __restrict__ nodes)
{
    int e4  = blockIdx.x * 256 + threadIdx.x;   // float4 index
    int row = e4 >> 4;
    int h4  = (e4 & 15) << 2;
    int id  = ids[row];
    *(float4*)(nodes + ((long)row << 6) + h4) =
        *(const float4*)(embed + ((long)id << 6) + h4);
}

// ---------------------------------------------------------------------------
// One tree level.
// grid.x = nodes_this_level / 64 (node tiles), grid.y = 64 (k)
// block = 256 threads.
// For each node: x (128 floats) = contiguous children rows [2i, 2i+1].
// Computes out[node][k] = tanh( x^T Vt[k] x + (x W)[k] + b[k] )
// ---------------------------------------------------------------------------
__global__ __launch_bounds__(256) void level_kernel(
    const float* __restrict__ prev, float* __restrict__ outp,
    const float* __restrict__ Vt, const float* __restrict__ W,
    const float* __restrict__ bias, int ln /* log2(n), n = nodes per batch */)
{
    __shared__ float xt[128][72];   // x transposed: xt[c][node], padded (72*4%16==0)
    __shared__ float vlds[8][128];  // Vt[k][c0..c0+7][0..127]

    const int t = threadIdx.x;
    const int k = blockIdx.y;
    const int n = 1 << ln;
    const long tile = blockIdx.x;

    // ---- stage x tile: 64 nodes x 128 floats (children are contiguous) ----
    #pragma unroll
    for (int q = 0; q < 8; ++q) {
        int idx = t + (q << 8);       // float4 index 0..2047
        int r   = idx >> 5;           // node row 0..63
        int fc  = idx & 31;           // float4 within the 128-float x
        long j  = (tile << 6) + r;    // flat node index this level
        long bb = j >> ln;
        long ii = j & (long)(n - 1);
        const float* src = prev + (((bb << ln) + ii) << 1) * 64 + (fc << 2);
        float4 v = *(const float4*)src;
        int c = fc << 2;
        xt[c + 0][r] = v.x;
        xt[c + 1][r] = v.y;
        xt[c + 2][r] = v.z;
        xt[c + 3][r] = v.w;
    }

    const int d0 = (t & 31) << 2;     // 4 d's per thread
    const int ng = t >> 5;            // node group 0..7 (8 nodes each)
    const float* vtk = Vt + ((long)k << 14);

    float acc[8][4];
    #pragma unroll
    for (int j = 0; j < 8; ++j)
        #pragma unroll
        for (int i = 0; i < 4; ++i) acc[j][i] = 0.f;

    for (int c0 = 0; c0 < 128; c0 += 8) {
        __syncthreads();              // (also covers xt staging on first iter)
        {   // stage Vt[k][c0..c0+7][:]: 1024 floats = 256 float4, one per thread
            int cc = t >> 5;
            int fd = t & 31;
            *(float4*)&vlds[cc][fd << 2] =
                *(const float4*)(vtk + ((long)(c0 + cc) << 7) + (fd << 2));
        }
        __syncthreads();
        #pragma unroll
        for (int cc = 0; cc < 8; ++cc) {
            const float4 v  = *(const float4*)&vlds[cc][d0];
            const float* xp = &xt[c0 + cc][ng << 3];
            const float4 xa = *(const float4*)(xp);
            const float4 xb = *(const float4*)(xp + 4);
            float xs[8] = {xa.x, xa.y, xa.z, xa.w, xb.x, xb.y, xb.z, xb.w};
            #pragma unroll
            for (int j = 0; j < 8; ++j) {
                acc[j][0] = fmaf(xs[j], v.x, acc[j][0]);
                acc[j][1] = fmaf(xs[j], v.y, acc[j][1]);
                acc[j][2] = fmaf(xs[j], v.z, acc[j][2]);
                acc[j][3] = fmaf(xs[j], v.w, acc[j][3]);
            }
        }
    }

    // ---- epilogue: bil = sum_d T[n,d]*x[n,d]; add Wx partials; reduce ----
    const int lane = t & 31;
    float red[8];
    #pragma unroll
    for (int j = 0; j < 8; ++j) {
        const int nl = (ng << 3) + j;
        float rsum = acc[j][0] * xt[d0 + 0][nl]
                   + acc[j][1] * xt[d0 + 1][nl]
                   + acc[j][2] * xt[d0 + 2][nl]
                   + acc[j][3] * xt[d0 + 3][nl];
        #pragma unroll
        for (int u = 0; u < 4; ++u) {      // Wx partial over c = lane*4..+3
            int c = (lane << 2) + u;
            rsum = fmaf(xt[c][nl], W[(c << 6) + k], rsum);
        }
        red[j] = rsum;
    }
    #pragma unroll
    for (int m = 1; m < 32; m <<= 1) {
        #pragma unroll
        for (int j = 0; j < 8; ++j)
            red[j] += __shfl_xor(red[j], m, 64);
    }
    if (lane == 0) {
        const float bk = bias[k];
        #pragma unroll
        for (int j = 0; j < 8; ++j) {
            long node = (tile << 6) + (ng << 3) + j;
            outp[(node << 6) + k] = tanhf(red[j] + bk);
        }
    }
}

// ---------------------------------------------------------------------------
// logits = nodes @ W_out (64x5), then log_softmax over the 5 outputs
// ---------------------------------------------------------------------------
__global__ __launch_bounds__(256) void out_kernel(
    const float* __restrict__ nodes, const float* __restrict__ Wout,
    float* __restrict__ out, int total)
{
    int r = blockIdx.x * 256 + threadIdx.x;
    if (r >= total) return;
    const float* x = nodes + ((long)r << 6);
    float acc[5] = {0.f, 0.f, 0.f, 0.f, 0.f};
    #pragma unroll
    for (int h = 0; h < 64; h += 4) {
        float4 v = *(const float4*)(x + h);
        float xv[4] = {v.x, v.y, v.z, v.w};
        #pragma unroll
        for (int u = 0; u < 4; ++u)
            #pragma unroll
            for (int o = 0; o < 5; ++o)
                acc[o] = fmaf(xv[u], Wout[(h + u) * 5 + o], acc[o]);
    }
    float m = acc[0];
    #pragma unroll
    for (int o = 1; o < 5; ++o) m = fmaxf(m, acc[o]);
    float s = 0.f;
    #pragma unroll
    for (int o = 0; o < 5; ++o) s += expf(acc[o] - m);
    float ls = logf(s);
    #pragma unroll
    for (int o = 0; o < 5; ++o) out[(long)r * 5 + o] = acc[o] - m - ls;
}

extern "C" void kernel_launch(void* const* d_in, const int* in_sizes, int n_in,
                              void* d_out, int out_size, void* d_ws, size_t ws_size,
                              hipStream_t stream) {
    const int*   ids   = (const int*)d_in[0];
    const float* embed = (const float*)d_in[1];
    const float* Vt    = (const float*)d_in[2];
    const float* W     = (const float*)d_in[3];
    const float* bias  = (const float*)d_in[4];
    const float* Wout  = (const float*)d_in[5];
    float* out   = (float*)d_out;
    float* nodes = (float*)d_ws;   // 130048 rows x 64 floats = 33.3 MB

    // level 0: leaves
    gather_leaves<<<4096, 256, 0, stream>>>(ids, embed, nodes);

    long off_prev = 0;
    long off_cur  = (long)BB * LL;     // 65536
    int  ln_prev  = 6;                 // log2(L)
    for (int lev = 0; lev < 6; ++lev) {
        int  ln = ln_prev - 1;         // 5,4,3,2,1,0
        long nl = (long)BB << ln;      // nodes this level
        dim3 grid((unsigned)(nl >> 6), 64);
        level_kernel<<<grid, 256, 0, stream>>>(nodes + (off_prev << 6),
                                               nodes + (off_cur << 6),
                                               Vt, W, bias, ln);
        off_prev = off_cur;
        off_cur += nl;
        ln_prev  = ln;
    }

    int total = (int)off_cur;          // 130048
    out_kernel<<<(total + 255) / 256, 256, 0, stream>>>(nodes, Wout, out, total);
}

// Round 3
// 374.318 us; speedup vs baseline: 5.5117x; 5.5117x over previous
//
#include <hip/hip_runtime.h>
#include <hip/hip_bf16.h>

#define BB 1024

typedef __attribute__((ext_vector_type(8))) short bf16x8;   // 8 bf16 = 4 VGPRs
typedef __attribute__((ext_vector_type(4))) float f32x4;    // MFMA C/D

__device__ __forceinline__ float bf2f(unsigned int u) {
    union { unsigned int i; float f; } v; v.i = u << 16; return v.f;
}
__device__ __forceinline__ unsigned short f2bf(float f) {
    union { float f; unsigned int i; } v; v.f = f;
    return (unsigned short)((v.i + 0x7fffu + ((v.i >> 16) & 1u)) >> 16);
}

// ---------------------------------------------------------------------------
// prep: blocks 0..63: VtB[k][d][c] = bf16(Vt[k][c][d]), 16B-blocks XOR-swizzled
//       (blk ^= d&7) within each 256B row, so linear global_load_lds +
//       swizzled ds_read_b128 is bank-conflict-free.
//       block 64: WT[k][c] = bf16(W[c][k]).
// ---------------------------------------------------------------------------
__global__ __launch_bounds__(256) void prep_kernel(
    const float* __restrict__ Vt, const float* __restrict__ W,
    char* __restrict__ VtB, unsigned short* __restrict__ WT)
{
    const int t = threadIdx.x;
    const int blk = blockIdx.x;
    if (blk < 64) {
        __shared__ float tile[64][132];
        const float* src = Vt + (size_t)blk * 16384;
        for (int h = 0; h < 2; ++h) {          // c-halves
            __syncthreads();
            for (int i = 0; i < 8; ++i) {      // stage 64c x 128d floats
                int f4 = t + i * 256;
                int cl = f4 >> 5;              // 0..63
                int d4 = (f4 & 31) << 2;
                const float* s4 = src + (size_t)(h * 64 + cl) * 128 + d4;
                float4 v = *(const float4*)s4;
                tile[cl][d4] = v.x; tile[cl][d4 + 1] = v.y;
                tile[cl][d4 + 2] = v.z; tile[cl][d4 + 3] = v.w;
            }
            __syncthreads();
            int d = t >> 1, ch = t & 1;
            for (int cb = h * 8 + ch * 4; cb < h * 8 + ch * 4 + 4; ++cb) {
                int cbl = cb - h * 8;
                unsigned int w[4];
                #pragma unroll
                for (int j = 0; j < 4; ++j) {
                    unsigned int lo = f2bf(tile[cbl * 8 + 2 * j][d]);
                    unsigned int hi = f2bf(tile[cbl * 8 + 2 * j + 1][d]);
                    w[j] = lo | (hi << 16);
                }
                int oblk = cb ^ (d & 7);
                *(uint4*)(VtB + (size_t)blk * 32768 + d * 256 + oblk * 16) =
                    make_uint4(w[0], w[1], w[2], w[3]);
            }
        }
    } else {
        for (int i = 0; i < 32; ++i) {
            int idx = t * 32 + i;
            int k = idx >> 7, c = idx & 127;
            WT[idx] = f2bf(W[c * 64 + k]);
        }
    }
}

// ---------------------------------------------------------------------------
// leaf gather -> bf16 node rows
// ---------------------------------------------------------------------------
__global__ __launch_bounds__(256) void gather_kernel(
    const int* __restrict__ ids, const float* __restrict__ embed,
    unsigned short* __restrict__ nodes)
{
    int e = blockIdx.x * 256 + threadIdx.x;  // 16B chunk, 8 per row
    int row = e >> 3;
    int part = e & 7;
    int id = ids[row];
    const float* src = embed + (size_t)id * 64 + part * 8;
    float4 a = *(const float4*)src;
    float4 b = *(const float4*)(src + 4);
    unsigned int w0 = (unsigned int)f2bf(a.x) | ((unsigned int)f2bf(a.y) << 16);
    unsigned int w1 = (unsigned int)f2bf(a.z) | ((unsigned int)f2bf(a.w) << 16);
    unsigned int w2 = (unsigned int)f2bf(b.x) | ((unsigned int)f2bf(b.y) << 16);
    unsigned int w3 = (unsigned int)f2bf(b.z) | ((unsigned int)f2bf(b.w) << 16);
    *(uint4*)(nodes + (size_t)row * 64 + part * 8) = make_uint4(w0, w1, w2, w3);
}

// ---------------------------------------------------------------------------
// One tree level, MFMA. Block: 512 thr (8 waves = 4 pairs x d-half),
// 256 nodes x 16 k. Per k: T = X(256x128) . Vt[k](128x128) via 16x16x32 bf16
// MFMA, then y[n] = sum_d T[n,d]*x[n,d] (Xe-packed LDS reads + shfl reduce).
// A-fragments (x rows) live in registers for all 16 k. Wx added by one extra
// MFMA pass with WT; tanh epilogue writes bf16.
// ---------------------------------------------------------------------------
__global__ __launch_bounds__(512, 2) void bil_kernel(
    unsigned short* __restrict__ nodes, const char* __restrict__ VtB,
    const unsigned short* __restrict__ WT, const float* __restrict__ bias,
    long prev_off, long out_off)
{
    extern __shared__ char smem[];
    char* Xe = smem;                    // 256 rows x 272B (256 data + 16 pad)
    char* vtb0 = smem + 69632;          // Vt double buffer 0 (32 KiB)
    char* vtb1 = smem + 69632 + 32768;  // Vt double buffer 1 (32 KiB)
    float* ylds = (float*)vtb0;         // post-loop alias (17408B <= 32768)

    const int t    = threadIdx.x;
    const int wave = t >> 6;
    const int lane = t & 63;
    const int q    = lane & 15;
    const int g    = lane >> 4;
    const int pair = wave >> 1;
    const int dh   = wave & 1;
    const int k0   = blockIdx.y * 16;
    const long nbase = (long)blockIdx.x * 256;

    const char* prevb = (const char*)(nodes + prev_off * 64); // x-row n at n*256

    // ---- build Xe: Xe[n][p], p = (d&15)*8 + (d>>4), bf16 ----
    {
        int r = t >> 1, hh = t & 1;
        const unsigned short* xrow = (const unsigned short*)(prevb + (nbase + r) * 256);
        for (int pb = 0; pb < 8; ++pb) {
            int p0 = hh * 64 + pb * 8;
            unsigned int w[4];
            #pragma unroll
            for (int j = 0; j < 4; ++j) {
                int pl = p0 + 2 * j, ph = p0 + 2 * j + 1;
                unsigned int lo = xrow[16 * (pl & 7) + (pl >> 3)];
                unsigned int hi = xrow[16 * (ph & 7) + (ph >> 3)];
                w[j] = lo | (hi << 16);
            }
            *(uint4*)(Xe + r * 272 + p0 * 2) = make_uint4(w[0], w[1], w[2], w[3]);
        }
    }

    // ---- A-fragment preload (registers, reused for all k) ----
    uint4 af[4][4];
    #pragma unroll
    for (int fm = 0; fm < 4; ++fm)
        #pragma unroll
        for (int s = 0; s < 4; ++s)
            af[fm][s] = *(const uint4*)(prevb + (nbase + pair * 64 + fm * 16 + q) * 256
                                        + (s * 32 + g * 8) * 2);

    // ---- stage Vt[k0] ----
    {
        const char* src = VtB + (size_t)k0 * 32768;
        for (int i = 0; i < 4; ++i) {
            char* ldsb = vtb0 + i * 8192 + wave * 1024;
            const char* gs = src + i * 8192 + wave * 1024 + lane * 16;
            __builtin_amdgcn_global_load_lds((const unsigned int*)gs,
                                             (unsigned int*)ldsb, 16, 0, 0);
        }
    }
    __syncthreads();

    float yreg[16];
    #pragma unroll
    for (int c = 0; c < 16; ++c) yreg[c] = 0.f;

    int cur = 0;
    for (int kk = 0; kk < 16; ++kk) {
        if (kk < 15) {  // prefetch next k into the buffer NOT being read
            const char* src = VtB + (size_t)(k0 + kk + 1) * 32768;
            char* dstb = (cur == 0) ? vtb1 : vtb0;
            for (int i = 0; i < 4; ++i) {
                char* ldsb = dstb + i * 8192 + wave * 1024;
                const char* gs = src + i * 8192 + wave * 1024 + lane * 16;
                __builtin_amdgcn_global_load_lds((const unsigned int*)gs,
                                                 (unsigned int*)ldsb, 16, 0, 0);
            }
        }

        f32x4 acc[4][4];
        #pragma unroll
        for (int fm = 0; fm < 4; ++fm)
            #pragma unroll
            for (int fn = 0; fn < 4; ++fn) acc[fm][fn] = (f32x4){0.f, 0.f, 0.f, 0.f};

        const char* vb = (cur == 0) ? vtb0 : vtb1;
        #pragma unroll
        for (int s = 0; s < 4; ++s) {
            #pragma unroll
            for (int fn = 0; fn < 4; ++fn) {
                int drow = (dh * 4 + fn) * 16 + q;
                int blk16 = (s * 4 + g) ^ (q & 7);
                bf16x8 bfrag = *(const bf16x8*)(vb + drow * 256 + blk16 * 16);
                #pragma unroll
                for (int fm = 0; fm < 4; ++fm) {
                    bf16x8 afr = *(const bf16x8*)&af[fm][s];
                    acc[fm][fn] = __builtin_amdgcn_mfma_f32_16x16x32_bf16(
                        afr, bfrag, acc[fm][fn], 0, 0, 0);
                }
            }
        }

        // epilogue: y[n] partial = sum over this wave's 64 d's
        #pragma unroll
        for (int fm = 0; fm < 4; ++fm) {
            #pragma unroll
            for (int reg = 0; reg < 4; ++reg) {
                int nl = pair * 64 + fm * 16 + g * 4 + reg;
                uint2 xv = *(const uint2*)(Xe + nl * 272 + q * 16 + dh * 8);
                float red = acc[fm][0][reg] * bf2f(xv.x & 0xffffu)
                          + acc[fm][1][reg] * bf2f(xv.x >> 16)
                          + acc[fm][2][reg] * bf2f(xv.y & 0xffffu)
                          + acc[fm][3][reg] * bf2f(xv.y >> 16);
                red += __shfl_xor(red, 1, 64);
                red += __shfl_xor(red, 2, 64);
                red += __shfl_xor(red, 4, 64);
                red += __shfl_xor(red, 8, 64);
                if (q == kk) yreg[fm * 4 + reg] = red;  // lane q keeps k = k0+q
            }
        }
        __syncthreads();   // drains prefetch (vmcnt) + protects buffer swap
        cur ^= 1;
    }

    // ---- cross-pair (d-half) combine + Wx + bias + tanh + store ----
    if (dh == 1) {
        #pragma unroll
        for (int c = 0; c < 16; ++c) {
            int nl = pair * 64 + (c >> 2) * 16 + g * 4 + (c & 3);
            ylds[nl * 17 + q] = yreg[c];
        }
    }
    __syncthreads();
    if (dh == 0) {
        f32x4 wx[4];
        #pragma unroll
        for (int fm = 0; fm < 4; ++fm) wx[fm] = (f32x4){0.f, 0.f, 0.f, 0.f};
        #pragma unroll
        for (int s = 0; s < 4; ++s) {
            bf16x8 wf = *(const bf16x8*)((const char*)WT + (k0 + q) * 256
                                         + (s * 32 + g * 8) * 2);
            #pragma unroll
            for (int fm = 0; fm < 4; ++fm) {
                bf16x8 afr = *(const bf16x8*)&af[fm][s];
                wx[fm] = __builtin_amdgcn_mfma_f32_16x16x32_bf16(afr, wf, wx[fm], 0, 0, 0);
            }
        }
        float bk = bias[k0 + q];
        unsigned short* outp = nodes + out_off * 64;
        #pragma unroll
        for (int c = 0; c < 16; ++c) {
            int fm = c >> 2, reg = c & 3;
            int nl = pair * 64 + fm * 16 + g * 4 + reg;
            float y = yreg[c] + ylds[nl * 17 + q] + wx[fm][reg] + bk;
            outp[(nbase + nl) * 64 + (k0 + q)] = f2bf(tanhf(y));
        }
    }
}

// ---------------------------------------------------------------------------
// logits + log_softmax (reads bf16 nodes)
// ---------------------------------------------------------------------------
__global__ __launch_bounds__(256) void out_kernel(
    const unsigned short* __restrict__ nodes, const float* __restrict__ Wout,
    float* __restrict__ out, int total)
{
    int r = blockIdx.x * 256 + threadIdx.x;
    if (r >= total) return;
    const uint4* xp = (const uint4*)(nodes + (size_t)r * 64);
    float acc[5] = {0.f, 0.f, 0.f, 0.f, 0.f};
    #pragma unroll
    for (int u4 = 0; u4 < 8; ++u4) {
        uint4 v = xp[u4];
        unsigned int ws[4] = {v.x, v.y, v.z, v.w};
        #pragma unroll
        for (int j = 0; j < 4; ++j) {
            int h = u4 * 8 + j * 2;
            float x0 = bf2f(ws[j] & 0xffffu);
            float x1 = bf2f(ws[j] >> 16);
            #pragma unroll
            for (int o = 0; o < 5; ++o) {
                acc[o] = fmaf(x0, Wout[h * 5 + o], acc[o]);
                acc[o] = fmaf(x1, Wout[(h + 1) * 5 + o], acc[o]);
            }
        }
    }
    float m = acc[0];
    #pragma unroll
    for (int o = 1; o < 5; ++o) m = fmaxf(m, acc[o]);
    float s = 0.f;
    #pragma unroll
    for (int o = 0; o < 5; ++o) s += expf(acc[o] - m);
    float ls = logf(s);
    #pragma unroll
    for (int o = 0; o < 5; ++o) out[(size_t)r * 5 + o] = acc[o] - m - ls;
}

extern "C" void kernel_launch(void* const* d_in, const int* in_sizes, int n_in,
                              void* d_out, int out_size, void* d_ws, size_t ws_size,
                              hipStream_t stream) {
    const int*   ids   = (const int*)d_in[0];
    const float* embed = (const float*)d_in[1];
    const float* Vt    = (const float*)d_in[2];
    const float* W     = (const float*)d_in[3];
    const float* bias  = (const float*)d_in[4];
    const float* Wout  = (const float*)d_in[5];
    float* out = (float*)d_out;

    char* ws = (char*)d_ws;
    unsigned short* nodes = (unsigned short*)ws;           // 130048*64*2 = 16,646,144 B
    char* VtB = ws + 16646144;                             // 64*32768 = 2,097,152 B
    unsigned short* WT = (unsigned short*)(ws + 18743296); // 16,384 B

    prep_kernel<<<65, 256, 0, stream>>>(Vt, W, VtB, WT);
    gather_kernel<<<2048, 256, 0, stream>>>(ids, embed, nodes);

    (void)hipFuncSetAttribute((const void*)bil_kernel,
                              hipFuncAttributeMaxDynamicSharedMemorySize, 135168);

    long off_prev = 0, off_cur = 65536;
    int n = 32;
    for (int lev = 0; lev < 6; ++lev) {
        long M = (long)BB * n;
        dim3 grid((unsigned)(M / 256), 4);
        bil_kernel<<<grid, 512, 135168, stream>>>(nodes, VtB, WT, bias,
                                                  off_prev, off_cur);
        off_prev = off_cur; off_cur += M; n >>= 1;
    }
    out_kernel<<<(130048 + 255) / 256, 256, 0, stream>>>(nodes, Wout, out, 130048);
}

// Round 4
// 258.833 us; speedup vs baseline: 7.9709x; 1.4462x over previous
//
#include <hip/hip_runtime.h>
#include <hip/hip_bf16.h>

#define BB 1024

typedef __attribute__((ext_vector_type(8))) short bf16x8;   // 8 bf16 = 4 VGPRs
typedef __attribute__((ext_vector_type(4))) float f32x4;    // MFMA C/D

__device__ __forceinline__ float bf2f(unsigned int u) {
    union { unsigned int i; float f; } v; v.i = u << 16; return v.f;
}
__device__ __forceinline__ unsigned short f2bf(float f) {
    union { float f; unsigned int i; } v; v.f = f;
    return (unsigned short)((v.i + 0x7fffu + ((v.i >> 16) & 1u)) >> 16);
}

// ---------------------------------------------------------------------------
// prep: blocks 0..63: VtB[k][d][c] = bf16(Vt[k][c][d]); within each 256B d-row
//       the 16B c-blocks are XOR-swizzled (blk ^= d&7) so linear
//       global_load_lds staging + swizzled ds_read_b128 is conflict-free.
//       block 64: WT[k][c] = bf16(W[c][k]).
// ---------------------------------------------------------------------------
__global__ __launch_bounds__(256) void prep_kernel(
    const float* __restrict__ Vt, const float* __restrict__ W,
    char* __restrict__ VtB, unsigned short* __restrict__ WT)
{
    const int t = threadIdx.x;
    const int blk = blockIdx.x;
    if (blk < 64) {
        __shared__ float tile[64][132];
        const float* src = Vt + (size_t)blk * 16384;
        for (int h = 0; h < 2; ++h) {          // c-halves
            __syncthreads();
            for (int i = 0; i < 8; ++i) {      // stage 64c x 128d floats
                int f4 = t + i * 256;
                int cl = f4 >> 5;              // 0..63
                int d4 = (f4 & 31) << 2;
                const float* s4 = src + (size_t)(h * 64 + cl) * 128 + d4;
                float4 v = *(const float4*)s4;
                tile[cl][d4] = v.x; tile[cl][d4 + 1] = v.y;
                tile[cl][d4 + 2] = v.z; tile[cl][d4 + 3] = v.w;
            }
            __syncthreads();
            int d = t >> 1, ch = t & 1;
            for (int cb = h * 8 + ch * 4; cb < h * 8 + ch * 4 + 4; ++cb) {
                int cbl = cb - h * 8;
                unsigned int w[4];
                #pragma unroll
                for (int j = 0; j < 4; ++j) {
                    unsigned int lo = f2bf(tile[cbl * 8 + 2 * j][d]);
                    unsigned int hi = f2bf(tile[cbl * 8 + 2 * j + 1][d]);
                    w[j] = lo | (hi << 16);
                }
                int oblk = cb ^ (d & 7);
                *(uint4*)(VtB + (size_t)blk * 32768 + d * 256 + oblk * 16) =
                    make_uint4(w[0], w[1], w[2], w[3]);
            }
        }
    } else {
        for (int i = 0; i < 32; ++i) {
            int idx = t * 32 + i;
            int k = idx >> 7, c = idx & 127;
            WT[idx] = f2bf(W[c * 64 + k]);
        }
    }
}

// ---------------------------------------------------------------------------
// leaf gather -> bf16 node rows
// ---------------------------------------------------------------------------
__global__ __launch_bounds__(256) void gather_kernel(
    const int* __restrict__ ids, const float* __restrict__ embed,
    unsigned short* __restrict__ nodes)
{
    int e = blockIdx.x * 256 + threadIdx.x;  // 16B chunk, 8 per row
    int row = e >> 3;
    int part = e & 7;
    int id = ids[row];
    const float* src = embed + (size_t)id * 64 + part * 8;
    float4 a = *(const float4*)src;
    float4 b = *(const float4*)(src + 4);
    unsigned int w0 = (unsigned int)f2bf(a.x) | ((unsigned int)f2bf(a.y) << 16);
    unsigned int w1 = (unsigned int)f2bf(a.z) | ((unsigned int)f2bf(a.w) << 16);
    unsigned int w2 = (unsigned int)f2bf(b.x) | ((unsigned int)f2bf(b.y) << 16);
    unsigned int w3 = (unsigned int)f2bf(b.z) | ((unsigned int)f2bf(b.w) << 16);
    *(uint4*)(nodes + (size_t)row * 64 + part * 8) = make_uint4(w0, w1, w2, w3);
}

// ---------------------------------------------------------------------------
// One tree level. Block: 512 thr = 8 waves = P(2 n-halves) x D(4 d-quarters).
// 128 nodes x 16 k per block. Swapped MFMA: C(d,n) = Vt[k](d,c) . x(n,c)^T,
// so the d-contraction y(n)=sum_d C(d,n)*x(n,d) is in-lane (reg) + 2-shfl
// g-reduce. Each wave self-stages its own 8KB Vt d-slice into a PRIVATE
// 16KB LDS double-buffer (global_load_lds + vmcnt(0)) -- no barriers in the
// k-loop. Wx via swapped MFMA with WT rows (matches yreg k-layout). Cross-
// wave d-combine + bias + tanh once per block through aliased LDS.
// ---------------------------------------------------------------------------
__global__ __launch_bounds__(512, 1) void bil_kernel(
    unsigned short* __restrict__ nodes, const char* __restrict__ VtB,
    const unsigned short* __restrict__ WT, const float* __restrict__ bias,
    long prev_off, long out_off)
{
    extern __shared__ char smem[];   // 8 waves x 16KB private dbuf = 128KB
    const int t    = threadIdx.x;
    const int wave = t >> 6;
    const int lane = t & 63;
    const int q    = lane & 15;      // MFMA col (n) / A-row (d) lane index
    const int g    = lane >> 4;      // 0..3
    const int p    = wave & 1;       // n-half (64 nodes)
    const int dq   = wave >> 1;      // d-quarter (32 d)
    const int k0   = blockIdx.y * 16;
    const long nbase = (long)blockIdx.x * 128;

    char* mybuf = smem + wave * 16384;
    const char* prevb = (const char*)(nodes + prev_off * 64); // x-row n at n*256

    // ---- x row pointers for this lane's 4 n-blocks ----
    const char* xrow[4];
    #pragma unroll
    for (int nb = 0; nb < 4; ++nb)
        xrow[nb] = prevb + (nbase + p * 64 + nb * 16 + q) * 256;

    // ---- B-fragments (x), registers, reused for all 16 k ----
    uint4 af[4][4];
    #pragma unroll
    for (int nb = 0; nb < 4; ++nb)
        #pragma unroll
        for (int s = 0; s < 4; ++s)
            af[nb][s] = *(const uint4*)(xrow[nb] + s * 64 + g * 16);

    // ---- epilogue x values (f32): d = dq*32 + db*16 + g*4 + r ----
    float xf[4][2][4];
    #pragma unroll
    for (int nb = 0; nb < 4; ++nb)
        #pragma unroll
        for (int db = 0; db < 2; ++db) {
            uint2 v = *(const uint2*)(xrow[nb] + (dq * 32 + db * 16 + g * 4) * 2);
            xf[nb][db][0] = bf2f(v.x & 0xffffu);
            xf[nb][db][1] = bf2f(v.x >> 16);
            xf[nb][db][2] = bf2f(v.y & 0xffffu);
            xf[nb][db][3] = bf2f(v.y >> 16);
        }

    // ---- stage k0 into parity-0 buffer (own 8KB d-slice) ----
    {
        const char* src = VtB + (size_t)k0 * 32768 + dq * 8192;
        #pragma unroll
        for (int i = 0; i < 8; ++i)
            __builtin_amdgcn_global_load_lds(
                (const unsigned int*)(src + i * 1024 + lane * 16),
                (unsigned int*)(mybuf + i * 1024 + lane * 16), 16, 0, 0);
    }
    asm volatile("s_waitcnt vmcnt(0)" ::: "memory");

    float yreg[16];
    #pragma unroll
    for (int c = 0; c < 16; ++c) yreg[c] = 0.f;

    #pragma unroll
    for (int kk = 0; kk < 16; ++kk) {
        const int par = kk & 1;
        const char* rbuf = mybuf + par * 8192;

        if (kk < 15) {  // stage next k into the other private buffer
            const char* src = VtB + (size_t)(k0 + kk + 1) * 32768 + dq * 8192;
            char* dbuf = mybuf + (par ^ 1) * 8192;
            #pragma unroll
            for (int i = 0; i < 8; ++i)
                __builtin_amdgcn_global_load_lds(
                    (const unsigned int*)(src + i * 1024 + lane * 16),
                    (unsigned int*)(dbuf + i * 1024 + lane * 16), 16, 0, 0);
        }

        // A-fragments (Vt rows d = dq*32 + db*16 + q)
        bf16x8 vf[2][4];
        #pragma unroll
        for (int db = 0; db < 2; ++db)
            #pragma unroll
            for (int s = 0; s < 4; ++s)
                vf[db][s] = *(const bf16x8*)(rbuf + (db * 16 + q) * 256
                                             + (((s * 4 + g) ^ (q & 7)) * 16));

        f32x4 acc[4][2];
        #pragma unroll
        for (int nb = 0; nb < 4; ++nb)
            #pragma unroll
            for (int db = 0; db < 2; ++db) acc[nb][db] = (f32x4){0.f, 0.f, 0.f, 0.f};

        #pragma unroll
        for (int s = 0; s < 4; ++s)
            #pragma unroll
            for (int nb = 0; nb < 4; ++nb) {
                bf16x8 bfr = *(const bf16x8*)&af[nb][s];
                #pragma unroll
                for (int db = 0; db < 2; ++db)
                    acc[nb][db] = __builtin_amdgcn_mfma_f32_16x16x32_bf16(
                        vf[db][s], bfr, acc[nb][db], 0, 0, 0);
            }

        // epilogue: in-lane d-contraction + 2-step g-reduce
        #pragma unroll
        for (int nb = 0; nb < 4; ++nb) {
            float red = 0.f;
            #pragma unroll
            for (int db = 0; db < 2; ++db)
                #pragma unroll
                for (int r = 0; r < 4; ++r)
                    red = fmaf(acc[nb][db][r], xf[nb][db][r], red);
            red += __shfl_xor(red, 16, 64);
            red += __shfl_xor(red, 32, 64);
            // lane keeps k = k0 + g*4 + slot  (slot = kk&3, when g == kk>>2)
            if (g == (kk >> 2)) yreg[nb * 4 + (kk & 3)] = red;
        }

        asm volatile("s_waitcnt vmcnt(0)" ::: "memory");
    }

    __syncthreads();   // k-loop done; dbuf LDS now dead -> alias Y

    // ---- Wx (dq==0 waves only): C(k,n) with A = WT rows k0..k0+15 ----
    if (dq == 0) {
        f32x4 accw[4];
        #pragma unroll
        for (int nb = 0; nb < 4; ++nb) accw[nb] = (f32x4){0.f, 0.f, 0.f, 0.f};
        #pragma unroll
        for (int s = 0; s < 4; ++s) {
            bf16x8 wtf = *(const bf16x8*)((const char*)WT + (k0 + q) * 256
                                          + s * 64 + g * 16);
            #pragma unroll
            for (int nb = 0; nb < 4; ++nb) {
                bf16x8 bfr = *(const bf16x8*)&af[nb][s];
                accw[nb] = __builtin_amdgcn_mfma_f32_16x16x32_bf16(
                    wtf, bfr, accw[nb], 0, 0, 0);
            }
        }
        // accw row = k0 + g*4 + r  == yreg slot r  -> direct add
        #pragma unroll
        for (int nb = 0; nb < 4; ++nb)
            #pragma unroll
            for (int r = 0; r < 4; ++r)
                yreg[nb * 4 + r] += accw[nb][r];
    }

    // ---- write partial Y[dq][n][klocal] (pad k-dim to 20 words) ----
    float* Y = (float*)smem;   // 4 x 128 x 20 x 4B = 40960B
    #pragma unroll
    for (int nb = 0; nb < 4; ++nb)
        #pragma unroll
        for (int slot = 0; slot < 4; ++slot)
            Y[dq * 2560 + (p * 64 + nb * 16 + q) * 20 + g * 4 + slot]
                = yreg[nb * 4 + slot];
    __syncthreads();

    // ---- final combine: sum 4 d-quarters, +bias, tanh, store bf16 ----
    {
        int n = t >> 2, kq = t & 3;
        float4 s0 = *(float4*)&Y[0 * 2560 + n * 20 + kq * 4];
        float4 s1 = *(float4*)&Y[1 * 2560 + n * 20 + kq * 4];
        float4 s2 = *(float4*)&Y[2 * 2560 + n * 20 + kq * 4];
        float4 s3 = *(float4*)&Y[3 * 2560 + n * 20 + kq * 4];
        float v0 = s0.x + s1.x + s2.x + s3.x + bias[k0 + kq * 4 + 0];
        float v1 = s0.y + s1.y + s2.y + s3.y + bias[k0 + kq * 4 + 1];
        float v2 = s0.z + s1.z + s2.z + s3.z + bias[k0 + kq * 4 + 2];
        float v3 = s0.w + s1.w + s2.w + s3.w + bias[k0 + kq * 4 + 3];
        unsigned int w0 = (unsigned int)f2bf(tanhf(v0))
                        | ((unsigned int)f2bf(tanhf(v1)) << 16);
        unsigned int w1 = (unsigned int)f2bf(tanhf(v2))
                        | ((unsigned int)f2bf(tanhf(v3)) << 16);
        unsigned short* outp = nodes + out_off * 64;
        *(uint2*)(outp + (nbase + n) * 64 + k0 + kq * 4) = make_uint2(w0, w1);
    }
}

// ---------------------------------------------------------------------------
// logits + log_softmax (reads bf16 nodes)
// ---------------------------------------------------------------------------
__global__ __launch_bounds__(256) void out_kernel(
    const unsigned short* __restrict__ nodes, const float* __restrict__ Wout,
    float* __restrict__ out, int total)
{
    int r = blockIdx.x * 256 + threadIdx.x;
    if (r >= total) return;
    const uint4* xp = (const uint4*)(nodes + (size_t)r * 64);
    float acc[5] = {0.f, 0.f, 0.f, 0.f, 0.f};
    #pragma unroll
    for (int u4 = 0; u4 < 8; ++u4) {
        uint4 v = xp[u4];
        unsigned int ws[4] = {v.x, v.y, v.z, v.w};
        #pragma unroll
        for (int j = 0; j < 4; ++j) {
            int h = u4 * 8 + j * 2;
            float x0 = bf2f(ws[j] & 0xffffu);
            float x1 = bf2f(ws[j] >> 16);
            #pragma unroll
            for (int o = 0; o < 5; ++o) {
                acc[o] = fmaf(x0, Wout[h * 5 + o], acc[o]);
                acc[o] = fmaf(x1, Wout[(h + 1) * 5 + o], acc[o]);
            }
        }
    }
    float m = acc[0];
    #pragma unroll
    for (int o = 1; o < 5; ++o) m = fmaxf(m, acc[o]);
    float s = 0.f;
    #pragma unroll
    for (int o = 0; o < 5; ++o) s += expf(acc[o] - m);
    float ls = logf(s);
    #pragma unroll
    for (int o = 0; o < 5; ++o) out[(size_t)r * 5 + o] = acc[o] - m - ls;
}

extern "C" void kernel_launch(void* const* d_in, const int* in_sizes, int n_in,
                              void* d_out, int out_size, void* d_ws, size_t ws_size,
                              hipStream_t stream) {
    const int*   ids   = (const int*)d_in[0];
    const float* embed = (const float*)d_in[1];
    const float* Vt    = (const float*)d_in[2];
    const float* W     = (const float*)d_in[3];
    const float* bias  = (const float*)d_in[4];
    const float* Wout  = (const float*)d_in[5];
    float* out = (float*)d_out;

    char* ws = (char*)d_ws;
    unsigned short* nodes = (unsigned short*)ws;           // 130048*64*2 = 16,646,144 B
    char* VtB = ws + 16646144;                             // 64*32768 = 2,097,152 B
    unsigned short* WT = (unsigned short*)(ws + 18743296); // 16,384 B

    prep_kernel<<<65, 256, 0, stream>>>(Vt, W, VtB, WT);
    gather_kernel<<<2048, 256, 0, stream>>>(ids, embed, nodes);

    (void)hipFuncSetAttribute((const void*)bil_kernel,
                              hipFuncAttributeMaxDynamicSharedMemorySize, 131072);

    long off_prev = 0, off_cur = 65536;
    int n = 32;
    for (int lev = 0; lev < 6; ++lev) {
        long M = (long)BB * n;                 // internal nodes this level
        dim3 grid((unsigned)(M / 128), 4);
        bil_kernel<<<grid, 512, 131072, stream>>>(nodes, VtB, WT, bias,
                                                  off_prev, off_cur);
        off_prev = off_cur; off_cur += M; n >>= 1;
    }
    out_kernel<<<(130048 + 255) / 256, 256, 0, stream>>>(nodes, Wout, out, 130048);
}